// Round 12
// baseline (1223.377 us; speedup 1.0000x reference)
//
#include <hip/hip_runtime.h>
#include <cmath>

#define NB 256            // 8 pair-groups x 32 unit blocks -> 1 block/CU
#define NT 512
#define NPG 8             // pair groups (each = 2 batch groups of 16 rows)
#define GB 32             // unit blocks per pair group
#define B_ 256
#define T_ 256
#define I_ 64
#define H_ 512
#define G4H 2048
#define BT 16             // rows per batch group
#define UT 16             // units per block -> 64 z cols
#define NFC 18            // K chunks of 32
#define NFCW 9            // chunks per wave (K-split pair)
#define CPQ 17            // cells (16B) per q-group: 16 rows + 1 pad
#define CSTR 68           // cell stride per chunk
#define NCELL 1224        // 18*68 cells per operand buffer
#define HPS_STR 20
#define R_ON_F 0.05f
#define ALPHA_F 1.0e-3f
#define LN_EPS_F 1.0e-5f

typedef _Float16 h8 __attribute__((ext_vector_type(8)));
typedef _Float16 h4v __attribute__((ext_vector_type(4)));
typedef float f4 __attribute__((ext_vector_type(4)));
typedef float v4f __attribute__((ext_vector_type(4)));

// Hidden-state double buffer; all accesses bypass caches (sc0 sc1).
__device__ __align__(16) float g_h[2][B_ * H_];

struct alignas(256) PadCnt { unsigned v; unsigned pad[63]; };
__device__ PadCnt g_cnt2[NPG];
__device__ PadCnt g_gen2[NPG];
__device__ PadCnt g_flag[16][GB];  // [batch group][unit block] = step count published

__device__ __forceinline__ float fast_sigmoid(float x) {
    return __builtin_amdgcn_rcpf(1.f + __expf(-x));
}
__device__ __forceinline__ float fast_tanh(float x) {
    return 1.f - 2.f * __builtin_amdgcn_rcpf(__expf(2.f * x) + 1.f);
}
// Barrier WITHOUT vmcnt drain: LDS-ordered only; global loads stay in flight.
__device__ __forceinline__ void bar_lgkm() {
    asm volatile("s_waitcnt lgkmcnt(0)\n\ts_barrier" ::: "memory");
}

struct HiLo { _Float16 hi, lo; };
__device__ __forceinline__ HiLo cvt_hilo(float v) {
    HiLo r;
    r.hi = (_Float16)v;
    r.lo = (_Float16)(v - (float)r.hi);
    return r;
}

__global__ __launch_bounds__(NT, 1) void plstm_scan_kernel(
    const float* __restrict__ x, const float* __restrict__ W,
    const float* __restrict__ U, const float* __restrict__ bias,
    const float* __restrict__ tau, const float* __restrict__ sph,
    const float* __restrict__ ln_g, const float* __restrict__ ln_b,
    const float* __restrict__ W1, const float* __restrict__ b1,
    const float* __restrict__ W2, const float* __restrict__ b2,
    float* __restrict__ out)
{
    __shared__ __align__(16) _Float16 AhA[NCELL * 8];  // 19.1 KB group-A operand
    __shared__ __align__(16) _Float16 AhB[NCELL * 8];  // 19.1 KB group-B operand
    __shared__ __align__(16) float zs[2][BT][68];      // 8.5 KB K-split partials (reused A/B)
    __shared__ __align__(16) float hpsA[BT * HPS_STR]; // fp32 hprev sidecars
    __shared__ __align__(16) float hpsB[BT * HPS_STR];
    __shared__ __align__(16) float bsz[64];
    __shared__ float red[16];

    const int tid = threadIdx.x;
    const int pg  = blockIdx.x >> 5;   // pair group 0..7
    const int ut2 = blockIdx.x & 31;   // unit block 0..31
    const int b0A = pg * 32;
    const int b0B = pg * 32 + 16;
    const int gA = 2 * pg, gB = 2 * pg + 1;
    const int u0 = ut2 * UT;

    // Zero own flags FIRST (graph replay leaves stale values).
    if (tid == 0) {
        unsigned z = 0;
        asm volatile(
            "global_store_dword %0, %2, off sc0 sc1\n\t"
            "global_store_dword %1, %2, off sc0 sc1\n\t"
            "s_waitcnt vmcnt(0)"
            :: "v"(&g_flag[gA][ut2].v), "v"(&g_flag[gB][ut2].v), "v"(z) : "memory");
    }

    const int wv = tid >> 6;
    const int lane = tid & 63;
    const int ntile = wv >> 1;         // gate 0..3
    const int kh = wv & 1;             // K half
    const int n_ = lane & 15;
    const int q_ = lane >> 4;

    // ---- one-time: B fragments (this wave's K half), fp16 hi/lo — shared by A and B ----
    const int jg = ntile * 512 + u0 + n_;
    h8 Bh[NFCW], Bl[NFCW];
    #pragma unroll
    for (int i = 0; i < NFCW; ++i) {
        const int cg = kh * NFCW + i;
        #pragma unroll
        for (int e = 0; e < 8; ++e) {
            const int kk = cg * 32 + q_ * 8 + e;
            float v;
            if (cg < 2) v = W[(size_t)kk * G4H + jg];
            else        v = U[(size_t)(kk - I_) * G4H + jg];
            const HiLo hl = cvt_hilo(v);
            Bh[i][e] = hl.hi;
            Bl[i][e] = hl.lo;
        }
    }
    if (tid < 64) bsz[tid] = bias[((tid >> 4) << 9) + u0 + (tid & 15)];

    // gate-update: H1 -> tid<256 (group A), H2 -> tid>=256 (group B); pair = (tid&255)
    const int uu = tid & 15;
    const float tau_r = tau[u0 + uu];
    const float s_r   = sph[u0 + uu];
    float c_st = 0.f;                  // A-state on tid<256, B-state on tid>=256

    // staging geometry (h exchange: 4 float4/thread covering 16 rows x 512 cols)
    const int hr0 = tid >> 7, hk4 = (tid & 127) << 2;
    const int cS = 2 + ((tid & 127) >> 3), qS = ((tid & 127) >> 1) & 3;
    const int e0s = (tid & 1) << 2;
    const int srcb = (tid & 127) >> 2;             // source unit block of my 4 cols
    const int mloc = (tid & 127) - (u0 >> 2);
    const bool own = (mloc >= 0) && (mloc < 4);
    const int dof = mloc << 2;
    // x staging: tid<256 -> group A rows, tid>=256 -> group B rows
    const int xth = tid & 255;
    const int xr = xth >> 4, xc4 = (xth & 15) << 2;
    const int cX = (xth & 15) >> 3, qX = ((xth & 15) >> 1) & 3;
    const int e0x = (xth & 1) << 2;
    const int fX = (cX * CSTR + qX * CPQ + xr) * 8 + e0x;

    const int fb = (kh * NFCW * CSTR + q_ * CPQ + n_) * 8;  // MFMA A-frag base

    // ---- pre-loop: zero operand buffers/sidecars, stage x(0) for A, prefetch ----
    {
        const h8 z8 = {};
        for (int idx = tid; idx < 2 * NCELL; idx += NT) {
            if (idx < NCELL) *(h8*)&AhA[idx * 8] = z8;
            else             *(h8*)&AhB[(idx - NCELL) * 8] = z8;
        }
        const v4f z4 = {0.f, 0.f, 0.f, 0.f};
        if (tid < 80)       *(v4f*)&hpsA[tid * 4] = z4;
        else if (tid < 160) *(v4f*)&hpsB[(tid - 80) * 4] = z4;
    }
    __syncthreads();
    float4 xvA = {0.f, 0.f, 0.f, 0.f}, xvB = {0.f, 0.f, 0.f, 0.f};
    if (tid < 256) {
        const float4 x0 = *(const float4*)(x + ((size_t)(b0A + xr) * T_ + 0) * I_ + xc4);
        h4v xh;
        xh[0] = (_Float16)x0.x; xh[1] = (_Float16)x0.y;
        xh[2] = (_Float16)x0.z; xh[3] = (_Float16)x0.w;
        *(h4v*)&AhA[fX] = xh;
        xvA = *(const float4*)(x + ((size_t)(b0A + xr) * T_ + 1) * I_ + xc4);
    } else {
        xvB = *(const float4*)(x + ((size_t)(b0B + xr) * T_ + 0) * I_ + xc4);
    }
    __syncthreads();
    // group barrier: all 32 blocks' flags zeroed before anyone publishes
    if (tid == 0) {
        unsigned gen = __hip_atomic_load(&g_gen2[pg].v, __ATOMIC_RELAXED, __HIP_MEMORY_SCOPE_SYSTEM);
        unsigned a = __hip_atomic_fetch_add(&g_cnt2[pg].v, 1u, __ATOMIC_RELAXED, __HIP_MEMORY_SCOPE_SYSTEM);
        if (a == GB - 1u) {
            __hip_atomic_store(&g_cnt2[pg].v, 0u, __ATOMIC_RELAXED, __HIP_MEMORY_SCOPE_SYSTEM);
            asm volatile("s_waitcnt vmcnt(0)" ::: "memory");
            __hip_atomic_store(&g_gen2[pg].v, gen + 1u, __ATOMIC_RELAXED, __HIP_MEMORY_SCOPE_SYSTEM);
        } else {
            while (__hip_atomic_load(&g_gen2[pg].v, __ATOMIC_RELAXED, __HIP_MEMORY_SCOPE_SYSTEM) == gen)
                __builtin_amdgcn_s_sleep(1);
        }
    }
    __syncthreads();

    int cur = 0;
    for (int t = 0; t < T_; ++t) {
        // ======== H1: group A step t ========
        // [1] MFMA A (AhA staged last iter)
        {
            f4 ac0 = {0.f, 0.f, 0.f, 0.f};
            f4 ac1 = {0.f, 0.f, 0.f, 0.f};
            #pragma unroll
            for (int i = 0; i < NFCW; ++i) {
                const h8 ah = *(const h8*)&AhA[fb + i * (CSTR * 8)];
                ac0 = __builtin_amdgcn_mfma_f32_16x16x32_f16(ah, Bh[i], ac0, 0, 0, 0);
                ac1 = __builtin_amdgcn_mfma_f32_16x16x32_f16(ah, Bl[i], ac1, 0, 0, 0);
            }
            const f4 zt = ac0 + ac1;
            const int colz = ntile * 16 + n_;
            const int rz = q_ * 4;
            zs[kh][rz + 0][colz] = zt[0];
            zs[kh][rz + 1][colz] = zt[1];
            zs[kh][rz + 2][colz] = zt[2];
            zs[kh][rz + 3][colz] = zt[3];
        }
        // [2] poll flagB>=t, issue hB(t) loads (fly through bar + gates)
        v4f a0 = {}, a1 = {}, a2 = {}, a3 = {};
        if (t > 0) {
            const unsigned want = (unsigned)t;
            const unsigned* fp2 = &g_flag[gB][srcb].v;
            unsigned v;
            do {
                asm volatile("global_load_dword %0, %1, off sc0 sc1\n\ts_waitcnt vmcnt(0)"
                             : "=v"(v) : "v"(fp2) : "memory");
            } while (__ballot(v < want));
            const float* hb = g_h[cur] + (size_t)(b0B + hr0) * H_ + hk4;
            asm volatile(
                "global_load_dwordx4 %0, %4, off sc0 sc1\n\t"
                "global_load_dwordx4 %1, %5, off sc0 sc1\n\t"
                "global_load_dwordx4 %2, %6, off sc0 sc1\n\t"
                "global_load_dwordx4 %3, %7, off sc0 sc1"
                : "=&v"(a0), "=&v"(a1), "=&v"(a2), "=&v"(a3)
                : "v"(hb), "v"(hb + 4 * H_), "v"(hb + 8 * H_), "v"(hb + 12 * H_)
                : "memory");
        }
        bar_lgkm();                                        // [3] zs visible
        // [4] gates A + stage AhB
        if (tid < 256) {
            const int ur = tid >> 4;
            const float zi = zs[0][ur][uu]      + zs[1][ur][uu]      + bsz[uu];
            const float zf = zs[0][ur][16 + uu] + zs[1][ur][16 + uu] + bsz[16 + uu];
            const float zg = zs[0][ur][32 + uu] + zs[1][ur][32 + uu] + bsz[32 + uu];
            const float zo = zs[0][ur][48 + uu] + zs[1][ur][48 + uu] + bsz[48 + uu];
            const float si = fast_sigmoid(zi);
            const float sf = fast_sigmoid(zf);
            const float so = fast_sigmoid(zo);
            const float ct = sf * c_st + si * fast_tanh(zg);
            const float ht = so * fast_tanh(ct);
            float aa = (float)t - s_r;
            float rr = fmodf(aa, tau_r);
            if (rr < 0.f) rr += tau_r;
            const float phi = rr / tau_r;
            float kk;
            if (phi < 0.5f * R_ON_F)      kk = phi * (2.f / R_ON_F);
            else if (phi < R_ON_F)        kk = 2.f - phi * (2.f / R_ON_F);
            else                          kk = ALPHA_F * phi;
            const float hprev = hpsA[ur * HPS_STR + uu];
            const float hn = kk * ht + (1.f - kk) * hprev;
            c_st = kk * ct + (1.f - kk) * c_st;
            float* gp = g_h[cur ^ 1] + (size_t)(b0A + ur) * H_ + (u0 + uu);
            asm volatile("global_store_dword %0, %1, off sc0 sc1" :: "v"(gp), "v"(hn) : "memory");
        }
        if (t > 0) {
            asm volatile("s_waitcnt vmcnt(0)"              // drains hA stores + hB loads
                : "+v"(a0), "+v"(a1), "+v"(a2), "+v"(a3) :: "memory");
            const v4f av[4] = {a0, a1, a2, a3};
            #pragma unroll
            for (int it = 0; it < 4; ++it) {
                const int row = hr0 + 4 * it;
                const int fidx = (cS * CSTR + qS * CPQ + row) * 8 + e0s;
                h4v hh;
                hh[0] = (_Float16)av[it][0]; hh[1] = (_Float16)av[it][1];
                hh[2] = (_Float16)av[it][2]; hh[3] = (_Float16)av[it][3];
                *(h4v*)&AhB[fidx] = hh;
                if (own) *(v4f*)&hpsB[row * HPS_STR + dof] = av[it];
            }
        } else {
            asm volatile("s_waitcnt vmcnt(0)" ::: "memory");
        }
        if (tid >= 256) {                                  // stage xB(t) into AhB
            h4v xh;
            xh[0] = (_Float16)xvB.x; xh[1] = (_Float16)xvB.y;
            xh[2] = (_Float16)xvB.z; xh[3] = (_Float16)xvB.w;
            *(h4v*)&AhB[fX] = xh;
            const int tn = (t < T_ - 1) ? t + 1 : T_ - 1;
            xvB = *(const float4*)(x + ((size_t)(b0B + xr) * T_ + tn) * I_ + xc4);
        }
        bar_lgkm();                                        // [5]
        if (tid == 0) {                                    // [6] publish flagA = t+1
            unsigned fv = (unsigned)(t + 1);
            asm volatile("global_store_dword %0, %1, off sc0 sc1"
                         :: "v"(&g_flag[gA][ut2].v), "v"(fv) : "memory");
        }

        // ======== H2: group B step t ========
        // [7] MFMA B
        {
            f4 ac0 = {0.f, 0.f, 0.f, 0.f};
            f4 ac1 = {0.f, 0.f, 0.f, 0.f};
            #pragma unroll
            for (int i = 0; i < NFCW; ++i) {
                const h8 ah = *(const h8*)&AhB[fb + i * (CSTR * 8)];
                ac0 = __builtin_amdgcn_mfma_f32_16x16x32_f16(ah, Bh[i], ac0, 0, 0, 0);
                ac1 = __builtin_amdgcn_mfma_f32_16x16x32_f16(ah, Bl[i], ac1, 0, 0, 0);
            }
            const f4 zt = ac0 + ac1;
            const int colz = ntile * 16 + n_;
            const int rz = q_ * 4;
            zs[kh][rz + 0][colz] = zt[0];
            zs[kh][rz + 1][colz] = zt[1];
            zs[kh][rz + 2][colz] = zt[2];
            zs[kh][rz + 3][colz] = zt[3];
        }
        // [8] poll flagA>=t+1 (published at [6]), issue hA(t+1) loads
        {
            const unsigned want = (unsigned)(t + 1);
            const unsigned* fp2 = &g_flag[gA][srcb].v;
            unsigned v;
            do {
                asm volatile("global_load_dword %0, %1, off sc0 sc1\n\ts_waitcnt vmcnt(0)"
                             : "=v"(v) : "v"(fp2) : "memory");
            } while (__ballot(v < want));
            const float* hb = g_h[cur ^ 1] + (size_t)(b0A + hr0) * H_ + hk4;
            asm volatile(
                "global_load_dwordx4 %0, %4, off sc0 sc1\n\t"
                "global_load_dwordx4 %1, %5, off sc0 sc1\n\t"
                "global_load_dwordx4 %2, %6, off sc0 sc1\n\t"
                "global_load_dwordx4 %3, %7, off sc0 sc1"
                : "=&v"(a0), "=&v"(a1), "=&v"(a2), "=&v"(a3)
                : "v"(hb), "v"(hb + 4 * H_), "v"(hb + 8 * H_), "v"(hb + 12 * H_)
                : "memory");
        }
        bar_lgkm();                                        // [9] zs visible
        // [10] gates B + stage AhA(t+1)
        if (tid >= 256) {
            const int ur = (tid & 255) >> 4;
            const float zi = zs[0][ur][uu]      + zs[1][ur][uu]      + bsz[uu];
            const float zf = zs[0][ur][16 + uu] + zs[1][ur][16 + uu] + bsz[16 + uu];
            const float zg = zs[0][ur][32 + uu] + zs[1][ur][32 + uu] + bsz[32 + uu];
            const float zo = zs[0][ur][48 + uu] + zs[1][ur][48 + uu] + bsz[48 + uu];
            const float si = fast_sigmoid(zi);
            const float sf = fast_sigmoid(zf);
            const float so = fast_sigmoid(zo);
            const float ct = sf * c_st + si * fast_tanh(zg);
            const float ht = so * fast_tanh(ct);
            float aa = (float)t - s_r;
            float rr = fmodf(aa, tau_r);
            if (rr < 0.f) rr += tau_r;
            const float phi = rr / tau_r;
            float kk;
            if (phi < 0.5f * R_ON_F)      kk = phi * (2.f / R_ON_F);
            else if (phi < R_ON_F)        kk = 2.f - phi * (2.f / R_ON_F);
            else                          kk = ALPHA_F * phi;
            const float hprev = hpsB[ur * HPS_STR + uu];
            const float hn = kk * ht + (1.f - kk) * hprev;
            c_st = kk * ct + (1.f - kk) * c_st;
            float* gp = g_h[cur ^ 1] + (size_t)(b0B + ur) * H_ + (u0 + uu);
            asm volatile("global_store_dword %0, %1, off sc0 sc1" :: "v"(gp), "v"(hn) : "memory");
        }
        {
            asm volatile("s_waitcnt vmcnt(0)"              // drains hB stores + hA loads
                : "+v"(a0), "+v"(a1), "+v"(a2), "+v"(a3) :: "memory");
            const v4f av[4] = {a0, a1, a2, a3};
            #pragma unroll
            for (int it = 0; it < 4; ++it) {
                const int row = hr0 + 4 * it;
                const int fidx = (cS * CSTR + qS * CPQ + row) * 8 + e0s;
                h4v hh;
                hh[0] = (_Float16)av[it][0]; hh[1] = (_Float16)av[it][1];
                hh[2] = (_Float16)av[it][2]; hh[3] = (_Float16)av[it][3];
                *(h4v*)&AhA[fidx] = hh;
                if (own) *(v4f*)&hpsA[row * HPS_STR + dof] = av[it];
            }
        }
        if (tid < 256) {                                   // stage xA(t+1) into AhA
            h4v xh;
            xh[0] = (_Float16)xvA.x; xh[1] = (_Float16)xvA.y;
            xh[2] = (_Float16)xvA.z; xh[3] = (_Float16)xvA.w;
            *(h4v*)&AhA[fX] = xh;
            const int tn = (t < T_ - 2) ? t + 2 : T_ - 1;
            xvA = *(const float4*)(x + ((size_t)(b0A + xr) * T_ + tn) * I_ + xc4);
        }
        bar_lgkm();                                        // [11]
        if (tid == 0) {                                    // [12] publish flagB = t+1
            unsigned fv = (unsigned)(t + 1);
            asm volatile("global_store_dword %0, %1, off sc0 sc1"
                         :: "v"(&g_flag[gB][ut2].v), "v"(fv) : "memory");
        }
        cur ^= 1;
    }

    // ---- epilogue: block b handles batch row b: LN + collapsed dense head ----
    {
        const int g = blockIdx.x >> 4;   // batch group of my row
        if (tid < 64) {
            const unsigned want = (unsigned)T_;
            const unsigned* fp2 = &g_flag[g][tid & 31].v;
            unsigned v;
            do {
                asm volatile("global_load_dword %0, %1, off sc0 sc1\n\ts_waitcnt vmcnt(0)"
                             : "=v"(v) : "v"(fp2) : "memory");
            } while (__ballot(v < want));
        }
        __syncthreads();

        const int b = blockIdx.x;
        float hv;
        const float* hp = g_h[cur] + (size_t)b * H_ + tid;
        asm volatile("global_load_dword %0, %1, off sc0 sc1\n\ts_waitcnt vmcnt(0)"
                     : "=v"(hv) : "v"(hp) : "memory");
        float s1 = hv, s2 = hv * hv;
        #pragma unroll
        for (int off = 32; off > 0; off >>= 1) {
            s1 += __shfl_down(s1, off, 64);
            s2 += __shfl_down(s2, off, 64);
        }
        const int ln = tid & 63;
        if (ln == 0) { red[wv] = s1; red[8 + wv] = s2; }
        __syncthreads();
        float S1 = 0.f, S2 = 0.f;
        #pragma unroll
        for (int w = 0; w < 8; ++w) { S1 += red[w]; S2 += red[8 + w]; }
        const float mu = S1 * (1.f / 512.f);
        const float var = S2 * (1.f / 512.f) - mu * mu;
        const float rstd = rsqrtf(var + LN_EPS_F);
        const float hn = (hv - mu) * rstd * ln_g[tid] + ln_b[tid];
        float w12 = 0.f;
        const float* w1p = W1 + (size_t)tid * 256;
        #pragma unroll 4
        for (int d = 0; d < 256; ++d) w12 = fmaf(w1p[d], W2[d], w12);
        float contrib = hn * w12;
        if (tid < 256) contrib = fmaf(b1[tid], W2[tid], contrib);
        #pragma unroll
        for (int off = 32; off > 0; off >>= 1) contrib += __shfl_down(contrib, off, 64);
        __syncthreads();
        if (ln == 0) red[wv] = contrib;
        __syncthreads();
        if (tid == 0) {
            float tot = b2[0];
            #pragma unroll
            for (int w = 0; w < 8; ++w) tot += red[w];
            out[b] = tot;
        }
    }
}

extern "C" void kernel_launch(void* const* d_in, const int* in_sizes, int n_in,
                              void* d_out, int out_size, void* d_ws, size_t ws_size,
                              hipStream_t stream) {
    const float* x   = (const float*)d_in[0];
    const float* W   = (const float*)d_in[1];
    const float* U   = (const float*)d_in[2];
    const float* b   = (const float*)d_in[3];
    const float* tau = (const float*)d_in[4];
    const float* s   = (const float*)d_in[5];
    const float* lng = (const float*)d_in[6];
    const float* lnb = (const float*)d_in[7];
    const float* W1  = (const float*)d_in[8];
    const float* b1  = (const float*)d_in[9];
    const float* W2  = (const float*)d_in[10];
    const float* b2  = (const float*)d_in[11];
    float* out = (float*)d_out;
    plstm_scan_kernel<<<dim3(NB), dim3(NT), 0, stream>>>(
        x, W, U, b, tau, s, lng, lnb, W1, b1, W2, b2, out);
}